// Round 11
// baseline (18662.428 us; speedup 1.0000x reference)
//
#include <hip/hip_runtime.h>
#include <cstdint>
#include <cmath>

#define FEAT 256
#define GATES 1024
#define BS 64
#define SEQ 2048
#define NEG_BIG -10000.0f
#define MIN_SEG 3.0f

#define KK_LDS 17                 // k-rows per chunk in LDS (136 KB total)
#define KPC 128                   // k-rows per chunk (2 chunks x 128 = 256)
#define NGEMM 192                 // gemm-role blocks in fused kernel

// ---- mode0 ws layout (floats) ----
#define M0_WPB  262144            // [1024] W_ih[:,0]
#define M0_BIAS 263168            // [1024] b_ih + b_hh
#define M0_H    264192            // [64][256]
#define M0_C    280576            // [64][256]
#define M0_PF   296960            // [64][2] prev,flag
#define M0_XP   297984            // two [T][64][1024] windows follow
// ---- mode1 fallback layout ----
#define M1_WIT  262144
#define M1_WPB  524288
#define M1_BIAS 525312

// consumer smem layout (floats)
#define S_WLDS 0                  // [34][1024] stationary LDS weights (136 KB)
#define S_PART 34816              // [2][1024]
#define S_XP   36864              // [2][1024]
#define S_H    38912              // [256]
#define S_RED  39168              // [8]
#define S_PV   39176              // [2]
#define S_TOT  39178              // 156.7 KB (cap 160 KB)

template<int MODE>
__global__ __launch_bounds__(1024) void prep_kernel(
    const float* __restrict__ W_ih, const float* __restrict__ W_hh,
    const float* __restrict__ b_ih, const float* __restrict__ b_hh,
    float* __restrict__ ws)
{
    const int k = blockIdx.x;    // 0..255
    const int j = threadIdx.x;   // 0..1023
    ws[k * GATES + j] = W_hh[(size_t)j * FEAT + k];          // WT[k][j]
    if (MODE == 1)
        ws[M1_WIT + k * GATES + j] = W_ih[(size_t)j * (FEAT + 1) + 1 + k];
    if (k == 0) {
        const int WPB = MODE ? M1_WPB : M0_WPB;
        const int BIA = MODE ? M1_BIAS : M0_BIAS;
        ws[WPB + j] = W_ih[(size_t)j * (FEAT + 1)];
        ws[BIA + j] = b_ih[j] + b_hh[j];
    }
    if (MODE == 0 && k == 1) {
#pragma unroll
        for (int i = 0; i < 16; ++i) {
            ws[M0_H + i * 1024 + j] = 0.f;
            ws[M0_C + i * 1024 + j] = 0.f;
        }
        if (j < 128) ws[M0_PF + j] = 0.f;
    }
}

// Prologue GEMM (window 0 only): XP[trow][b][j] = x(t0+trow) @ W_ih[:,1:]^T + bias
__global__ __launch_bounds__(256) void xproj_gemm(
    const float* __restrict__ x, const float* __restrict__ W_ih,
    float* __restrict__ ws, int t0, int xpoff)
{
    const int trow = blockIdx.y;
    const int t  = t0 + trow;
    const int j0 = blockIdx.x * 64;
    const int tid = threadIdx.x;
    const int ty = tid >> 4, tx = tid & 15;
    const float* bias = ws + M0_BIAS;
    float* XP = ws + xpoff;
    __shared__ __align__(16) float As[64][65];
    __shared__ __align__(16) float Bs[64][65];
    float acc[4][4] = {};
    for (int k0 = 0; k0 < FEAT; k0 += 64) {
#pragma unroll
        for (int i = 0; i < 16; ++i) {
            int idx = i * 256 + tid;
            int rr = idx >> 6, cc = idx & 63;
            As[rr][cc] = x[((size_t)rr * SEQ + t) * FEAT + k0 + cc];
        }
#pragma unroll
        for (int i = 0; i < 16; ++i) {
            int idx = i * 256 + tid;
            int jj = idx >> 6, kk = idx & 63;
            Bs[kk][jj] = W_ih[(size_t)(j0 + jj) * (FEAT + 1) + 1 + k0 + kk];
        }
        __syncthreads();
#pragma unroll
        for (int kk = 0; kk < 64; ++kk) {
            float a[4], bv[4];
#pragma unroll
            for (int r = 0; r < 4; ++r) a[r] = As[ty * 4 + r][kk];
#pragma unroll
            for (int c = 0; c < 4; ++c) bv[c] = Bs[kk][tx * 4 + c];
#pragma unroll
            for (int r = 0; r < 4; ++r)
#pragma unroll
                for (int c = 0; c < 4; ++c)
                    acc[r][c] = fmaf(a[r], bv[c], acc[r][c]);
        }
        __syncthreads();
    }
#pragma unroll
    for (int r = 0; r < 4; ++r) {
        int bb = ty * 4 + r;
        size_t base = ((size_t)trow * BS + bb) * GATES + j0 + tx * 4;
        float4 v;
        v.x = acc[r][0] + bias[j0 + tx * 4 + 0];
        v.y = acc[r][1] + bias[j0 + tx * 4 + 1];
        v.z = acc[r][2] + bias[j0 + tx * 4 + 2];
        v.w = acc[r][3] + bias[j0 + tx * 4 + 3];
        *(float4*)&XP[base] = v;
    }
}

#define FMA4(acc, hb, wv) \
    acc.x = fmaf(hb, wv.x, acc.x); acc.y = fmaf(hb, wv.y, acc.y); \
    acc.z = fmaf(hb, wv.z, acc.z); acc.w = fmaf(hb, wv.w, acc.w);

// Heterogeneous kernel, 512 threads/block: blocks 0..63 = recurrence;
// blocks 64..255 = GEMM producing next chunk's XP. Disjoint ws regions;
// kernel boundary is the only producer->consumer sync.
// __launch_bounds__(512, 2): LDS (156.7 KB) forces 1 block/CU = 2 waves/EU,
// so declaring min 2 waves/EU is free and legitimizes a 256-VGPR budget.
template<int KREG>
__global__ __launch_bounds__(512, 2) void fused_kernel(
    const float* __restrict__ x, const float* __restrict__ W_ih,
    float* __restrict__ ws,
    const float* __restrict__ Wp, const float* __restrict__ bp,
    float* __restrict__ out_b, float* __restrict__ out_sel,
    int t0, int Tlen, int xp_cur, int xp_nxt)
{
    __shared__ __align__(16) float smem[S_TOT];   // 156.7 KB, overlaid per role
    const int tid = threadIdx.x;

    if (blockIdx.x >= BS) {
        // ================= GEMM role =================
        if (xp_nxt < 0) return;
        float* As = smem;            // [64][65]
        float* Bs = smem + 4160;     // [64][260] (float4-aligned rows)
        const float* bias = ws + M0_BIAS;
        float* XPn = ws + xp_nxt;
        const int tx = tid & 63, ty = tid >> 6;   // ty uniform per wave
        const int jobs = Tlen * 4;                // (trow, j-quarter of 256)
        for (int job = blockIdx.x - BS; job < jobs; job += NGEMM) {
            const int trow = job >> 2;
            const int j0 = (job & 3) * 256;
            const int t = t0 + Tlen + trow;
            float acc[8][4] = {};
            for (int k0 = 0; k0 < FEAT; k0 += 64) {
                __syncthreads();                   // WAR on LDS reuse
#pragma unroll
                for (int i = 0; i < 8; ++i) {
                    int idx = i * 512 + tid, rr = idx >> 6, cc = idx & 63;
                    As[rr * 65 + cc] = x[((size_t)rr * SEQ + t) * FEAT + k0 + cc];
                }
#pragma unroll
                for (int i = 0; i < 32; ++i) {
                    int idx = i * 512 + tid, jj = idx >> 6, kk = idx & 63;
                    Bs[kk * 260 + jj] = W_ih[(size_t)(j0 + jj) * (FEAT + 1) + 1 + k0 + kk];
                }
                __syncthreads();
#pragma unroll 4
                for (int kk = 0; kk < 64; ++kk) {
                    float4 bv = *(const float4*)&Bs[kk * 260 + tx * 4];
#pragma unroll
                    for (int r = 0; r < 8; ++r) {
                        float a = As[(ty * 8 + r) * 65 + kk];
                        acc[r][0] = fmaf(a, bv.x, acc[r][0]);
                        acc[r][1] = fmaf(a, bv.y, acc[r][1]);
                        acc[r][2] = fmaf(a, bv.z, acc[r][2]);
                        acc[r][3] = fmaf(a, bv.w, acc[r][3]);
                    }
                }
            }
#pragma unroll
            for (int r = 0; r < 8; ++r) {
                int bb = ty * 8 + r;
                size_t base = ((size_t)trow * BS + bb) * GATES + j0 + tx * 4;
                float4 v;
                v.x = acc[r][0] + bias[j0 + tx * 4 + 0];
                v.y = acc[r][1] + bias[j0 + tx * 4 + 1];
                v.z = acc[r][2] + bias[j0 + tx * 4 + 2];
                v.w = acc[r][3] + bias[j0 + tx * 4 + 3];
                *(float4*)&XPn[base] = v;
            }
        }
        return;
    }

    // ================= consumer role =================
    const int b   = blockIdx.x;
    const int ch  = tid >> 8;          // k-chunk 0..1 (128 k-rows each)
    const int j4  = (tid & 255) * 4;   // gate quad
    const int f   = tid & 255;         // feature (phase-2 role, tid<256)
    const int kbase = ch * KPC;

    const float* WT  = ws;
    const float* WPB = ws + M0_WPB;
    float* H  = ws + M0_H;
    float* C  = ws + M0_C;
    float* PF = ws + M0_PF;
    const float* XPc = ws + xp_cur;

    float* wlds   = smem + S_WLDS;
    float* part   = smem + S_PART;
    float* xp_lds = smem + S_XP;
    float* h_lds  = smem + S_H;
    float* red    = smem + S_RED;
    float* s_pv   = smem + S_PV;

    // stationary weights: registers (KREG float4/thread)
    float4 wreg[KREG];
#pragma unroll
    for (int kk = 0; kk < KREG; ++kk)
        wreg[kk] = *(const float4*)&WT[(size_t)(kbase + kk) * GATES + j4];
    // stationary weights: LDS (rows KREG..KREG+16 of each chunk, 136 KB)
    for (int i = 0; i < (2 * KK_LDS * 1024) / 512; ++i) {
        int idx = i * 512 + tid;
        int row = idx >> 10, col = idx & 1023;
        int ch2 = row / KK_LDS, kkl = row % KK_LDS;
        wlds[row * 1024 + col] = WT[(size_t)(ch2 * KPC + KREG + kkl) * GATES + col];
    }

    float wpbr[4] = {};
    float wp0 = 0.f, wp1 = 0.f, c_reg = 0.f;
    if (tid < FEAT) {
#pragma unroll
        for (int g = 0; g < 4; ++g) wpbr[g] = WPB[g * FEAT + f];
        wp0 = Wp[f]; wp1 = Wp[FEAT + f];
        c_reg = C[b * FEAT + f];
        h_lds[f] = H[b * FEAT + f];
    }
    const float bp0 = bp[0], bp1 = bp[1];
    xp_lds[tid]       = XPc[(size_t)b * GATES + tid];         // window row 0
    xp_lds[tid + 512] = XPc[(size_t)b * GATES + tid + 512];
    if (tid == 0) { s_pv[0] = PF[b * 2 + 0]; s_pv[1] = PF[b * 2 + 1]; }
    __syncthreads();

    float fl_r = 0.f;
    if (tid == 0) fl_r = s_pv[1];

    for (int tl = 0; tl < Tlen; ++tl) {
        const int t   = t0 + tl;
        const int buf = tl & 1;

        // prefetch next step's xp row (2 floats/thread)
        float xpf0 = 0.f, xpf1 = 0.f;
        const bool haspf = (tl + 1 < Tlen);
        if (haspf) {
            const float* xr = XPc + ((size_t)(tl + 1) * BS + b) * GATES;
            xpf0 = xr[tid]; xpf1 = xr[tid + 512];
        }

        // ---- phase 1: gate matvec (all 8 waves) ----
        float4 acc = make_float4(0.f, 0.f, 0.f, 0.f);
#pragma unroll
        for (int kk = 0; kk < KREG; ++kk) {
            float hb = h_lds[kbase + kk];
            FMA4(acc, hb, wreg[kk]);
        }
#pragma unroll
        for (int kk = 0; kk < KK_LDS; ++kk) {
            float hb = h_lds[kbase + KREG + kk];
            float4 wv = *(const float4*)&wlds[(ch * KK_LDS + kk) * 1024 + j4];
            FMA4(acc, hb, wv);
        }
#pragma unroll 16
        for (int kk = KREG + KK_LDS; kk < KPC; ++kk) {
            float hb = h_lds[kbase + kk];
            float4 wv = *(const float4*)&WT[(size_t)(kbase + kk) * GATES + j4];
            FMA4(acc, hb, wv);
        }
        *(float4*)&part[ch * 1024 + j4] = acc;
        __syncthreads();                                     // A

        if (haspf) {
            xp_lds[(buf ^ 1) * 1024 + tid]       = xpf0;
            xp_lds[(buf ^ 1) * 1024 + tid + 512] = xpf1;
        }

        // ---- phase 2: gate combine + LSTM + policy (threads 0..255) ----
        if (tid < FEAT) {
            const float pvv = s_pv[0];
            float gv[4];
#pragma unroll
            for (int g = 0; g < 4; ++g) {
                const int jj = g * FEAT + f;
                gv[g] = part[jj] + part[1024 + jj]
                      + xp_lds[buf * 1024 + jj] + pvv * wpbr[g];
            }
            float ig = 1.f / (1.f + expf(-gv[0]));
            float fg = 1.f / (1.f + expf(-gv[1]));
            float gt = tanhf(gv[2]);
            float og = 1.f / (1.f + expf(-gv[3]));
            c_reg = fg * c_reg + ig * gt;
            float h = og * tanhf(c_reg);
            h_lds[f] = h;
            if (tl == Tlen - 1) {
                H[b * FEAT + f] = h;
                C[b * FEAT + f] = c_reg;
            }
            float p0 = h * wp0, p1 = h * wp1;
#pragma unroll
            for (int off = 32; off > 0; off >>= 1) {
                p0 += __shfl_xor(p0, off, 64);
                p1 += __shfl_xor(p1, off, 64);
            }
            if ((tid & 63) == 0) {
                red[tid >> 6] = p0;
                red[4 + (tid >> 6)] = p1;
            }
        }
        __syncthreads();                                     // B

        // ---- phase 3: decision (tid 0); s_pv consumers are behind barrier A
        // of step t+1 (proven pattern).
        if (tid == 0) {
            float l0 = red[0] + red[1] + red[2] + red[3] + bp0;
            float l1 = red[4] + red[5] + red[6] + red[7] + bp1;
            if (fl_r > 0.0f) l1 += NEG_BIG;
            int samp = (l1 > l0) ? 1 : 0;
            float a0 = l0 * 0.5f, a1 = l1 * 0.5f;   // logits / TAU, TAU = 2
            float m = fmaxf(a0, a1);
            float lse = m + logf(expf(a0 - m) + expf(a1 - m));
            out_b[(size_t)b * SEQ + t]   = (float)samp;
            out_sel[(size_t)b * SEQ + t] = (samp ? a1 : a0) - lse;
            fl_r = (fl_r > 0.0f) ? (fl_r - 1.0f) : fl_r;
            if (samp) fl_r = MIN_SEG;
            s_pv[0] = (float)samp;
            if (tl == Tlen - 1) {
                PF[b * 2 + 0] = (float)samp;
                PF[b * 2 + 1] = fl_r;
            }
        }
    }
}

// ---- mode1 fallback (tiny ws): fused streaming consumer (r5-proven) ----
__global__ __launch_bounds__(1024) void consumer1(
    const float* __restrict__ x, float* __restrict__ ws,
    const float* __restrict__ Wp, const float* __restrict__ bp,
    float* __restrict__ out_b, float* __restrict__ out_sel)
{
    const int b   = blockIdx.x;
    const int tid = threadIdx.x;
    const int ch  = tid >> 8;
    const int j4  = (tid & 255) * 4;
    const int f   = tid & 255;
    const int kbase = ch * 64;

    const float* WT   = ws;
    const float* WIT  = ws + M1_WIT;
    const float* WPB  = ws + M1_WPB;
    const float* BIAS = ws + M1_BIAS;

    __shared__ __align__(16) float part[4][GATES];
    __shared__ __align__(16) float h_lds[FEAT];
    __shared__ __align__(16) float x_lds[2][FEAT];
    __shared__ float red[8];
    __shared__ float s_pv[2];

    float biasr[4] = {}, wpbr[4] = {};
    float wp0 = 0.f, wp1 = 0.f, c_reg = 0.f;
    if (tid < FEAT) {
#pragma unroll
        for (int g = 0; g < 4; ++g) {
            wpbr[g]  = WPB[g * FEAT + f];
            biasr[g] = BIAS[g * FEAT + f];
        }
        wp0 = Wp[f]; wp1 = Wp[FEAT + f];
        h_lds[f] = 0.f;
        x_lds[0][f] = x[(size_t)b * SEQ * FEAT + f];
    }
    const float bp0 = bp[0], bp1 = bp[1];
    if (tid == 0) { s_pv[0] = 0.f; s_pv[1] = 0.f; }
    __syncthreads();

    float fl_r = 0.f;
    for (int t = 0; t < SEQ; ++t) {
        const int buf = t & 1;
        float xpf = 0.f;
        const bool haspf = (t + 1 < SEQ) && (tid < FEAT);
        if (haspf) xpf = x[((size_t)b * SEQ + (t + 1)) * FEAT + f];

        float4 acc = make_float4(0.f, 0.f, 0.f, 0.f);
#pragma unroll 4
        for (int kk = 0; kk < 64; ++kk) {
            float hb = h_lds[kbase + kk];
            float4 wv = *(const float4*)&WT[(size_t)(kbase + kk) * GATES + j4];
            FMA4(acc, hb, wv);
            float xb = x_lds[buf][kbase + kk];
            float4 wi = *(const float4*)&WIT[(size_t)(kbase + kk) * GATES + j4];
            FMA4(acc, xb, wi);
        }
        *(float4*)&part[ch][j4] = acc;
        __syncthreads();
        if (haspf) x_lds[buf ^ 1][f] = xpf;

        if (tid < FEAT) {
            const float pvv = s_pv[0];
            float gv[4];
#pragma unroll
            for (int g = 0; g < 4; ++g) {
                const int jj = g * FEAT + f;
                gv[g] = part[0][jj] + part[1][jj] + part[2][jj] + part[3][jj]
                      + biasr[g] + pvv * wpbr[g];
            }
            float ig = 1.f / (1.f + expf(-gv[0]));
            float fg = 1.f / (1.f + expf(-gv[1]));
            float gt = tanhf(gv[2]);
            float og = 1.f / (1.f + expf(-gv[3]));
            c_reg = fg * c_reg + ig * gt;
            float h = og * tanhf(c_reg);
            h_lds[f] = h;
            float p0 = h * wp0, p1 = h * wp1;
#pragma unroll
            for (int off = 32; off > 0; off >>= 1) {
                p0 += __shfl_xor(p0, off, 64);
                p1 += __shfl_xor(p1, off, 64);
            }
            if ((tid & 63) == 0) { red[tid >> 6] = p0; red[4 + (tid >> 6)] = p1; }
        }
        __syncthreads();

        if (tid == 0) {
            float l0 = red[0] + red[1] + red[2] + red[3] + bp0;
            float l1 = red[4] + red[5] + red[6] + red[7] + bp1;
            if (fl_r > 0.0f) l1 += NEG_BIG;
            int samp = (l1 > l0) ? 1 : 0;
            float a0 = l0 * 0.5f, a1 = l1 * 0.5f;
            float m = fmaxf(a0, a1);
            float lse = m + logf(expf(a0 - m) + expf(a1 - m));
            out_b[(size_t)b * SEQ + t]   = (float)samp;
            out_sel[(size_t)b * SEQ + t] = (samp ? a1 : a0) - lse;
            fl_r = (fl_r > 0.0f) ? (fl_r - 1.0f) : fl_r;
            if (samp) fl_r = MIN_SEG;
            s_pv[0] = (float)samp;
        }
    }
}

extern "C" void kernel_launch(void* const* d_in, const int* in_sizes, int n_in,
                              void* d_out, int out_size, void* d_ws, size_t ws_size,
                              hipStream_t stream)
{
    const float* x    = (const float*)d_in[0];
    // d_in[1] = label (unused by the reference forward)
    const float* W_ih = (const float*)d_in[2];
    const float* W_hh = (const float*)d_in[3];
    const float* b_ih = (const float*)d_in[4];
    const float* b_hh = (const float*)d_in[5];
    const float* Wp   = (const float*)d_in[6];
    const float* bp   = (const float*)d_in[7];

    float* ws      = (float*)d_ws;
    float* out_b   = (float*)d_out;
    float* out_sel = out_b + (size_t)BS * SEQ;

    // largest T with TWO XP windows fitting in ws
    int T = 0;
    for (int cand = 256; cand >= 8; cand >>= 1) {
        size_t need = ((size_t)M0_XP + 2 * (size_t)cand * BS * GATES) * sizeof(float);
        if (ws_size >= need) { T = cand; break; }
    }

    if (T > 0) {
        // Adaptive KREG selection (host-only, capture-safe): pick the largest
        // variant whose compiled artifact shows the weights truly in registers
        // (numRegs >= 4*KREG+16) with no scratch spill. Fallback = 40 (r10 cfg).
        static const int cand_kreg[3] = {56, 52, 44};
        const void* cand_fn[3] = {
            reinterpret_cast<const void*>(&fused_kernel<56>),
            reinterpret_cast<const void*>(&fused_kernel<52>),
            reinterpret_cast<const void*>(&fused_kernel<44>)
        };
        int pick = 40;
        for (int i = 0; i < 3; ++i) {
            hipFuncAttributes fa;
            if (hipFuncGetAttributes(&fa, cand_fn[i]) == hipSuccess &&
                fa.localSizeBytes < 128 &&
                fa.numRegs >= cand_kreg[i] * 4 + 16) {
                pick = cand_kreg[i];
                break;
            }
        }

        hipLaunchKernelGGL((prep_kernel<0>), dim3(FEAT), dim3(GATES), 0, stream,
                           W_ih, W_hh, b_ih, b_hh, ws);
        const int win_f = T * BS * GATES;
        const int nch = SEQ / T;
        hipLaunchKernelGGL(xproj_gemm, dim3(GATES / 64, T), dim3(256), 0, stream,
                           x, W_ih, ws, 0, M0_XP);
        for (int c = 0; c < nch; ++c) {
            const int xp_cur = M0_XP + (c & 1) * win_f;
            const int xp_nxt = (c + 1 < nch) ? (M0_XP + ((c + 1) & 1) * win_f) : -1;
            switch (pick) {
            case 56:
                hipLaunchKernelGGL((fused_kernel<56>), dim3(BS + NGEMM), dim3(512), 0,
                                   stream, x, W_ih, ws, Wp, bp, out_b, out_sel,
                                   c * T, T, xp_cur, xp_nxt);
                break;
            case 52:
                hipLaunchKernelGGL((fused_kernel<52>), dim3(BS + NGEMM), dim3(512), 0,
                                   stream, x, W_ih, ws, Wp, bp, out_b, out_sel,
                                   c * T, T, xp_cur, xp_nxt);
                break;
            case 44:
                hipLaunchKernelGGL((fused_kernel<44>), dim3(BS + NGEMM), dim3(512), 0,
                                   stream, x, W_ih, ws, Wp, bp, out_b, out_sel,
                                   c * T, T, xp_cur, xp_nxt);
                break;
            default:
                hipLaunchKernelGGL((fused_kernel<40>), dim3(BS + NGEMM), dim3(512), 0,
                                   stream, x, W_ih, ws, Wp, bp, out_b, out_sel,
                                   c * T, T, xp_cur, xp_nxt);
                break;
            }
        }
    } else {
        hipLaunchKernelGGL((prep_kernel<1>), dim3(FEAT), dim3(GATES), 0, stream,
                           W_ih, W_hh, b_ih, b_hh, ws);
        hipLaunchKernelGGL(consumer1, dim3(BS), dim3(1024), 0, stream,
                           x, ws, Wp, bp, out_b, out_sel);
    }
}

// Round 12
// 11408.240 us; speedup vs baseline: 1.6359x; 1.6359x over previous
//
#include <hip/hip_runtime.h>
#include <cstdint>
#include <cmath>

#define FEAT 256
#define GATES 1024
#define BS 64
#define SEQ 2048
#define NEG_BIG -10000.0f
#define MIN_SEG 3.0f

#define KK_REG 40                 // k-rows per chunk in VGPRs (proven-best cfg)
#define KK_LDS 16                 // k-rows per chunk in LDS (128 KB total)
#define KK_STA (KK_REG + KK_LDS)  // 56 of 128 rows/chunk stationary
#define KPC 128                   // k-rows per chunk (2 chunks x 128 = 256)
#define NGEMM 192                 // gemm-role blocks in fused kernel

// ---- mode0 ws layout (floats) ----
#define M0_WPB  262144            // [1024] W_ih[:,0]
#define M0_BIAS 263168            // [1024] b_ih + b_hh
#define M0_H    264192            // [64][256]
#define M0_C    280576            // [64][256]
#define M0_PF   296960            // [64][2] prev,flag
#define M0_XP   297984            // two [T][64][1024] windows follow
// ---- mode1 fallback layout ----
#define M1_WIT  262144
#define M1_WPB  524288
#define M1_BIAS 525312

// consumer smem layout (floats)
#define S_WLDS 0                  // [32][1024] stationary LDS weights
#define S_PART 32768              // [2][1024]
#define S_XP   34816              // [2][1024]
#define S_H    36864              // [256]
#define S_RED  37120              // [8]
#define S_PV   37128              // [2]
#define S_TOT  37130              // 148.5 KB

template<int MODE>
__global__ __launch_bounds__(1024) void prep_kernel(
    const float* __restrict__ W_ih, const float* __restrict__ W_hh,
    const float* __restrict__ b_ih, const float* __restrict__ b_hh,
    float* __restrict__ ws)
{
    const int k = blockIdx.x;    // 0..255
    const int j = threadIdx.x;   // 0..1023
    ws[k * GATES + j] = W_hh[(size_t)j * FEAT + k];          // WT[k][j]
    if (MODE == 1)
        ws[M1_WIT + k * GATES + j] = W_ih[(size_t)j * (FEAT + 1) + 1 + k];
    if (k == 0) {
        const int WPB = MODE ? M1_WPB : M0_WPB;
        const int BIA = MODE ? M1_BIAS : M0_BIAS;
        ws[WPB + j] = W_ih[(size_t)j * (FEAT + 1)];
        ws[BIA + j] = b_ih[j] + b_hh[j];
    }
    if (MODE == 0 && k == 1) {
#pragma unroll
        for (int i = 0; i < 16; ++i) {
            ws[M0_H + i * 1024 + j] = 0.f;
            ws[M0_C + i * 1024 + j] = 0.f;
        }
        if (j < 128) ws[M0_PF + j] = 0.f;
    }
}

// Prologue GEMM (window 0 only): XP[trow][b][j] = x(t0+trow) @ W_ih[:,1:]^T + bias
__global__ __launch_bounds__(256) void xproj_gemm(
    const float* __restrict__ x, const float* __restrict__ W_ih,
    float* __restrict__ ws, int t0, int xpoff)
{
    const int trow = blockIdx.y;
    const int t  = t0 + trow;
    const int j0 = blockIdx.x * 64;
    const int tid = threadIdx.x;
    const int ty = tid >> 4, tx = tid & 15;
    const float* bias = ws + M0_BIAS;
    float* XP = ws + xpoff;
    __shared__ __align__(16) float As[64][65];
    __shared__ __align__(16) float Bs[64][65];
    float acc[4][4] = {};
    for (int k0 = 0; k0 < FEAT; k0 += 64) {
#pragma unroll
        for (int i = 0; i < 16; ++i) {
            int idx = i * 256 + tid;
            int rr = idx >> 6, cc = idx & 63;
            As[rr][cc] = x[((size_t)rr * SEQ + t) * FEAT + k0 + cc];
        }
#pragma unroll
        for (int i = 0; i < 16; ++i) {
            int idx = i * 256 + tid;
            int jj = idx >> 6, kk = idx & 63;
            Bs[kk][jj] = W_ih[(size_t)(j0 + jj) * (FEAT + 1) + 1 + k0 + kk];
        }
        __syncthreads();
#pragma unroll
        for (int kk = 0; kk < 64; ++kk) {
            float a[4], bv[4];
#pragma unroll
            for (int r = 0; r < 4; ++r) a[r] = As[ty * 4 + r][kk];
#pragma unroll
            for (int c = 0; c < 4; ++c) bv[c] = Bs[kk][tx * 4 + c];
#pragma unroll
            for (int r = 0; r < 4; ++r)
#pragma unroll
                for (int c = 0; c < 4; ++c)
                    acc[r][c] = fmaf(a[r], bv[c], acc[r][c]);
        }
        __syncthreads();
    }
#pragma unroll
    for (int r = 0; r < 4; ++r) {
        int bb = ty * 4 + r;
        size_t base = ((size_t)trow * BS + bb) * GATES + j0 + tx * 4;
        float4 v;
        v.x = acc[r][0] + bias[j0 + tx * 4 + 0];
        v.y = acc[r][1] + bias[j0 + tx * 4 + 1];
        v.z = acc[r][2] + bias[j0 + tx * 4 + 2];
        v.w = acc[r][3] + bias[j0 + tx * 4 + 3];
        *(float4*)&XP[base] = v;
    }
}

#define FMA4(acc, hb, wv) \
    acc.x = fmaf(hb, wv.x, acc.x); acc.y = fmaf(hb, wv.y, acc.y); \
    acc.z = fmaf(hb, wv.z, acc.z); acc.w = fmaf(hb, wv.w, acc.w);

// Heterogeneous kernel, 512 threads/block: blocks 0..63 = recurrence;
// blocks 64..255 = GEMM producing next chunk's XP. Disjoint ws regions;
// kernel boundary is the only producer->consumer sync.
__global__ __launch_bounds__(512) void fused_kernel(
    const float* __restrict__ x, const float* __restrict__ W_ih,
    float* __restrict__ ws,
    const float* __restrict__ Wp, const float* __restrict__ bp,
    float* __restrict__ out_b, float* __restrict__ out_sel,
    int t0, int Tlen, int xp_cur, int xp_nxt)
{
    __shared__ __align__(16) float smem[S_TOT];   // 148.5 KB, overlaid per role
    const int tid = threadIdx.x;

    if (blockIdx.x >= BS) {
        // ================= GEMM role =================
        if (xp_nxt < 0) return;
        float* As = smem;            // [64][65]
        float* Bs = smem + 4160;     // [64][260] (float4-aligned rows)
        const float* bias = ws + M0_BIAS;
        float* XPn = ws + xp_nxt;
        const int tx = tid & 63, ty = tid >> 6;   // ty uniform per wave
        const int jobs = Tlen * 4;                // (trow, j-quarter of 256)
        for (int job = blockIdx.x - BS; job < jobs; job += NGEMM) {
            const int trow = job >> 2;
            const int j0 = (job & 3) * 256;
            const int t = t0 + Tlen + trow;
            float acc[8][4] = {};
            for (int k0 = 0; k0 < FEAT; k0 += 64) {
                __syncthreads();                   // WAR on LDS reuse
#pragma unroll
                for (int i = 0; i < 8; ++i) {
                    int idx = i * 512 + tid, rr = idx >> 6, cc = idx & 63;
                    As[rr * 65 + cc] = x[((size_t)rr * SEQ + t) * FEAT + k0 + cc];
                }
#pragma unroll
                for (int i = 0; i < 32; ++i) {
                    int idx = i * 512 + tid, jj = idx >> 6, kk = idx & 63;
                    Bs[kk * 260 + jj] = W_ih[(size_t)(j0 + jj) * (FEAT + 1) + 1 + k0 + kk];
                }
                __syncthreads();
#pragma unroll 4
                for (int kk = 0; kk < 64; ++kk) {
                    float4 bv = *(const float4*)&Bs[kk * 260 + tx * 4];
#pragma unroll
                    for (int r = 0; r < 8; ++r) {
                        float a = As[(ty * 8 + r) * 65 + kk];
                        acc[r][0] = fmaf(a, bv.x, acc[r][0]);
                        acc[r][1] = fmaf(a, bv.y, acc[r][1]);
                        acc[r][2] = fmaf(a, bv.z, acc[r][2]);
                        acc[r][3] = fmaf(a, bv.w, acc[r][3]);
                    }
                }
            }
#pragma unroll
            for (int r = 0; r < 8; ++r) {
                int bb = ty * 8 + r;
                size_t base = ((size_t)trow * BS + bb) * GATES + j0 + tx * 4;
                float4 v;
                v.x = acc[r][0] + bias[j0 + tx * 4 + 0];
                v.y = acc[r][1] + bias[j0 + tx * 4 + 1];
                v.z = acc[r][2] + bias[j0 + tx * 4 + 2];
                v.w = acc[r][3] + bias[j0 + tx * 4 + 3];
                *(float4*)&XPn[base] = v;
            }
        }
        return;
    }

    // ================= consumer role =================
    const int b   = blockIdx.x;
    const int ch  = tid >> 8;          // k-chunk 0..1 (128 k-rows each)
    const int j4  = (tid & 255) * 4;   // gate quad
    const int f   = tid & 255;         // feature (phase-2 role, tid<256)
    const int kbase = ch * KPC;

    const float* WT  = ws;
    const float* WPB = ws + M0_WPB;
    float* H  = ws + M0_H;
    float* C  = ws + M0_C;
    float* PF = ws + M0_PF;
    const float* XPc = ws + xp_cur;

    float* wlds   = smem + S_WLDS;
    float* part   = smem + S_PART;
    float* xp_lds = smem + S_XP;
    float* h_lds  = smem + S_H;
    float* red    = smem + S_RED;
    float* s_pv   = smem + S_PV;

    // stationary weights: registers (40 float4 requested)
    float4 wreg[KK_REG];
#pragma unroll
    for (int kk = 0; kk < KK_REG; ++kk)
        wreg[kk] = *(const float4*)&WT[(size_t)(kbase + kk) * GATES + j4];
    // stationary weights: LDS (rows KK_REG..KK_STA-1 of each chunk, 128 KB)
#pragma unroll
    for (int i = 0; i < 64; ++i) {
        int idx = i * 512 + tid;
        int row = idx >> 10, col = idx & 1023;
        int ch2 = row >> 4, kkl = row & 15;
        wlds[row * 1024 + col] = WT[(size_t)(ch2 * KPC + KK_REG + kkl) * GATES + col];
    }

    float wpbr[4] = {};
    float wp0 = 0.f, wp1 = 0.f, c_reg = 0.f;
    if (tid < FEAT) {
#pragma unroll
        for (int g = 0; g < 4; ++g) wpbr[g] = WPB[g * FEAT + f];
        wp0 = Wp[f]; wp1 = Wp[FEAT + f];
        c_reg = C[b * FEAT + f];
        h_lds[f] = H[b * FEAT + f];
    }
    const float bp0 = bp[0], bp1 = bp[1];
    xp_lds[tid]       = XPc[(size_t)b * GATES + tid];         // window row 0
    xp_lds[tid + 512] = XPc[(size_t)b * GATES + tid + 512];
    if (tid == 0) { s_pv[0] = PF[b * 2 + 0]; s_pv[1] = PF[b * 2 + 1]; }
    __syncthreads();

    float fl_r = 0.f;
    if (tid == 0) fl_r = s_pv[1];

    for (int tl = 0; tl < Tlen; ++tl) {
        const int t   = t0 + tl;
        const int buf = tl & 1;

        // prefetch next step's xp row (2 floats/thread)
        float xpf0 = 0.f, xpf1 = 0.f;
        const bool haspf = (tl + 1 < Tlen);
        if (haspf) {
            const float* xr = XPc + ((size_t)(tl + 1) * BS + b) * GATES;
            xpf0 = xr[tid]; xpf1 = xr[tid + 512];
        }

        // ---- phase 1: gate matvec (all 8 waves) ----
        float4 acc = make_float4(0.f, 0.f, 0.f, 0.f);
#pragma unroll
        for (int kk = 0; kk < KK_REG; ++kk) {
            float hb = h_lds[kbase + kk];
            FMA4(acc, hb, wreg[kk]);
        }
#pragma unroll
        for (int kk = 0; kk < KK_LDS; ++kk) {
            float hb = h_lds[kbase + KK_REG + kk];
            float4 wv = *(const float4*)&wlds[(ch * KK_LDS + kk) * 1024 + j4];
            FMA4(acc, hb, wv);
        }
#pragma unroll 8
        for (int kk = KK_STA; kk < KPC; ++kk) {
            float hb = h_lds[kbase + kk];
            float4 wv = *(const float4*)&WT[(size_t)(kbase + kk) * GATES + j4];
            FMA4(acc, hb, wv);
        }
        *(float4*)&part[ch * 1024 + j4] = acc;
        __syncthreads();                                     // A

        if (haspf) {
            xp_lds[(buf ^ 1) * 1024 + tid]       = xpf0;
            xp_lds[(buf ^ 1) * 1024 + tid + 512] = xpf1;
        }

        // ---- phase 2: gate combine + LSTM + policy (threads 0..255) ----
        if (tid < FEAT) {
            const float pvv = s_pv[0];
            float gv[4];
#pragma unroll
            for (int g = 0; g < 4; ++g) {
                const int jj = g * FEAT + f;
                gv[g] = part[jj] + part[1024 + jj]
                      + xp_lds[buf * 1024 + jj] + pvv * wpbr[g];
            }
            float ig = 1.f / (1.f + expf(-gv[0]));
            float fg = 1.f / (1.f + expf(-gv[1]));
            float gt = tanhf(gv[2]);
            float og = 1.f / (1.f + expf(-gv[3]));
            c_reg = fg * c_reg + ig * gt;
            float h = og * tanhf(c_reg);
            h_lds[f] = h;
            if (tl == Tlen - 1) {
                H[b * FEAT + f] = h;
                C[b * FEAT + f] = c_reg;
            }
            float p0 = h * wp0, p1 = h * wp1;
#pragma unroll
            for (int off = 32; off > 0; off >>= 1) {
                p0 += __shfl_xor(p0, off, 64);
                p1 += __shfl_xor(p1, off, 64);
            }
            if ((tid & 63) == 0) {
                red[tid >> 6] = p0;
                red[4 + (tid >> 6)] = p1;
            }
        }
        __syncthreads();                                     // B

        // ---- phase 3: decision (tid 0); s_pv consumers are behind barrier A
        // of step t+1 (proven pattern).
        if (tid == 0) {
            float l0 = red[0] + red[1] + red[2] + red[3] + bp0;
            float l1 = red[4] + red[5] + red[6] + red[7] + bp1;
            if (fl_r > 0.0f) l1 += NEG_BIG;
            int samp = (l1 > l0) ? 1 : 0;
            float a0 = l0 * 0.5f, a1 = l1 * 0.5f;   // logits / TAU, TAU = 2
            float m = fmaxf(a0, a1);
            float lse = m + logf(expf(a0 - m) + expf(a1 - m));
            out_b[(size_t)b * SEQ + t]   = (float)samp;
            out_sel[(size_t)b * SEQ + t] = (samp ? a1 : a0) - lse;
            fl_r = (fl_r > 0.0f) ? (fl_r - 1.0f) : fl_r;
            if (samp) fl_r = MIN_SEG;
            s_pv[0] = (float)samp;
            if (tl == Tlen - 1) {
                PF[b * 2 + 0] = (float)samp;
                PF[b * 2 + 1] = fl_r;
            }
        }
    }
}

// ---- mode1 fallback (tiny ws): fused streaming consumer (r5-proven) ----
__global__ __launch_bounds__(1024) void consumer1(
    const float* __restrict__ x, float* __restrict__ ws,
    const float* __restrict__ Wp, const float* __restrict__ bp,
    float* __restrict__ out_b, float* __restrict__ out_sel)
{
    const int b   = blockIdx.x;
    const int tid = threadIdx.x;
    const int ch  = tid >> 8;
    const int j4  = (tid & 255) * 4;
    const int f   = tid & 255;
    const int kbase = ch * 64;

    const float* WT   = ws;
    const float* WIT  = ws + M1_WIT;
    const float* WPB  = ws + M1_WPB;
    const float* BIAS = ws + M1_BIAS;

    __shared__ __align__(16) float part[4][GATES];
    __shared__ __align__(16) float h_lds[FEAT];
    __shared__ __align__(16) float x_lds[2][FEAT];
    __shared__ float red[8];
    __shared__ float s_pv[2];

    float biasr[4] = {}, wpbr[4] = {};
    float wp0 = 0.f, wp1 = 0.f, c_reg = 0.f;
    if (tid < FEAT) {
#pragma unroll
        for (int g = 0; g < 4; ++g) {
            wpbr[g]  = WPB[g * FEAT + f];
            biasr[g] = BIAS[g * FEAT + f];
        }
        wp0 = Wp[f]; wp1 = Wp[FEAT + f];
        h_lds[f] = 0.f;
        x_lds[0][f] = x[(size_t)b * SEQ * FEAT + f];
    }
    const float bp0 = bp[0], bp1 = bp[1];
    if (tid == 0) { s_pv[0] = 0.f; s_pv[1] = 0.f; }
    __syncthreads();

    float fl_r = 0.f;
    for (int t = 0; t < SEQ; ++t) {
        const int buf = t & 1;
        float xpf = 0.f;
        const bool haspf = (t + 1 < SEQ) && (tid < FEAT);
        if (haspf) xpf = x[((size_t)b * SEQ + (t + 1)) * FEAT + f];

        float4 acc = make_float4(0.f, 0.f, 0.f, 0.f);
#pragma unroll 4
        for (int kk = 0; kk < 64; ++kk) {
            float hb = h_lds[kbase + kk];
            float4 wv = *(const float4*)&WT[(size_t)(kbase + kk) * GATES + j4];
            FMA4(acc, hb, wv);
            float xb = x_lds[buf][kbase + kk];
            float4 wi = *(const float4*)&WIT[(size_t)(kbase + kk) * GATES + j4];
            FMA4(acc, xb, wi);
        }
        *(float4*)&part[ch][j4] = acc;
        __syncthreads();
        if (haspf) x_lds[buf ^ 1][f] = xpf;

        if (tid < FEAT) {
            const float pvv = s_pv[0];
            float gv[4];
#pragma unroll
            for (int g = 0; g < 4; ++g) {
                const int jj = g * FEAT + f;
                gv[g] = part[0][jj] + part[1][jj] + part[2][jj] + part[3][jj]
                      + biasr[g] + pvv * wpbr[g];
            }
            float ig = 1.f / (1.f + expf(-gv[0]));
            float fg = 1.f / (1.f + expf(-gv[1]));
            float gt = tanhf(gv[2]);
            float og = 1.f / (1.f + expf(-gv[3]));
            c_reg = fg * c_reg + ig * gt;
            float h = og * tanhf(c_reg);
            h_lds[f] = h;
            float p0 = h * wp0, p1 = h * wp1;
#pragma unroll
            for (int off = 32; off > 0; off >>= 1) {
                p0 += __shfl_xor(p0, off, 64);
                p1 += __shfl_xor(p1, off, 64);
            }
            if ((tid & 63) == 0) { red[tid >> 6] = p0; red[4 + (tid >> 6)] = p1; }
        }
        __syncthreads();

        if (tid == 0) {
            float l0 = red[0] + red[1] + red[2] + red[3] + bp0;
            float l1 = red[4] + red[5] + red[6] + red[7] + bp1;
            if (fl_r > 0.0f) l1 += NEG_BIG;
            int samp = (l1 > l0) ? 1 : 0;
            float a0 = l0 * 0.5f, a1 = l1 * 0.5f;
            float m = fmaxf(a0, a1);
            float lse = m + logf(expf(a0 - m) + expf(a1 - m));
            out_b[(size_t)b * SEQ + t]   = (float)samp;
            out_sel[(size_t)b * SEQ + t] = (samp ? a1 : a0) - lse;
            fl_r = (fl_r > 0.0f) ? (fl_r - 1.0f) : fl_r;
            if (samp) fl_r = MIN_SEG;
            s_pv[0] = (float)samp;
        }
    }
}

extern "C" void kernel_launch(void* const* d_in, const int* in_sizes, int n_in,
                              void* d_out, int out_size, void* d_ws, size_t ws_size,
                              hipStream_t stream)
{
    const float* x    = (const float*)d_in[0];
    // d_in[1] = label (unused by the reference forward)
    const float* W_ih = (const float*)d_in[2];
    const float* W_hh = (const float*)d_in[3];
    const float* b_ih = (const float*)d_in[4];
    const float* b_hh = (const float*)d_in[5];
    const float* Wp   = (const float*)d_in[6];
    const float* bp   = (const float*)d_in[7];

    float* ws      = (float*)d_ws;
    float* out_b   = (float*)d_out;
    float* out_sel = out_b + (size_t)BS * SEQ;

    // largest T with TWO XP windows fitting in ws
    int T = 0;
    for (int cand = 128; cand >= 8; cand >>= 1) {
        size_t need = ((size_t)M0_XP + 2 * (size_t)cand * BS * GATES) * sizeof(float);
        if (ws_size >= need) { T = cand; break; }
    }

    if (T > 0) {
        hipLaunchKernelGGL((prep_kernel<0>), dim3(FEAT), dim3(GATES), 0, stream,
                           W_ih, W_hh, b_ih, b_hh, ws);
        const int win_f = T * BS * GATES;      // window size in floats
        const int nch = SEQ / T;
        // prologue: window 0
        hipLaunchKernelGGL(xproj_gemm, dim3(GATES / 64, T), dim3(256), 0, stream,
                           x, W_ih, ws, 0, M0_XP);
        for (int c = 0; c < nch; ++c) {
            const int xp_cur = M0_XP + (c & 1) * win_f;
            const int xp_nxt = (c + 1 < nch) ? (M0_XP + ((c + 1) & 1) * win_f) : -1;
            hipLaunchKernelGGL(fused_kernel, dim3(BS + NGEMM), dim3(512), 0, stream,
                               x, W_ih, ws, Wp, bp, out_b, out_sel,
                               c * T, T, xp_cur, xp_nxt);
        }
    } else {
        hipLaunchKernelGGL((prep_kernel<1>), dim3(FEAT), dim3(GATES), 0, stream,
                           W_ih, W_hh, b_ih, b_hh, ws);
        hipLaunchKernelGGL(consumer1, dim3(BS), dim3(1024), 0, stream,
                           x, ws, Wp, bp, out_b, out_sel);
    }
}